// Round 3
// baseline (109.090 us; speedup 1.0000x reference)
//
#include <hip/hip_runtime.h>
#include <stdint.h>

// FibonacciKAN: y[b,o] = sum_i sum_d F_d(tanh(x[b,i])) * C[i,o,d]
// F0..F5 = {0, 1, t, t^2+1, t^3+2t, t^4+3t^2+1}
// => y = bias[o] + sum_i ( t*W0 + t^2*W1 + t^3*W2 + t^4*W3 )[i,o]
// GEMM: M=32768, N=256, K=1024, bf16 MFMA 16x16x32.
//
// R3: K-loop rebuilt as parity double-buffer, unroll-2 (no bcur=bnxt register
// rotation -> no per-iter vmcnt(0) drain). Wave tiles = 4 M-strips x full
// N-128 (mt2 x nt8): all 4 waves load identical B-frag addresses -> L1 merge,
// L2 B-traffic /2. MFMA order per (m,n,k) unchanged -> absmax identical.

typedef short bf16x8 __attribute__((ext_vector_type(8)));
typedef float f32x4 __attribute__((ext_vector_type(4)));
typedef unsigned int uint4v __attribute__((ext_vector_type(4)));

__device__ __forceinline__ unsigned int pack_bf16_trunc(float a, float b) {
  return __builtin_amdgcn_perm(__float_as_uint(b), __float_as_uint(a), 0x07060302u);
}
__device__ __forceinline__ unsigned int round_bf16_bits(float a) {
  unsigned int u = __float_as_uint(a);
  return u + 0x7fffu + ((u >> 16) & 1u);
}
__device__ __forceinline__ unsigned int pack_bf16_rne(float a, float b) {
  return __builtin_amdgcn_perm(round_bf16_bits(b), round_bf16_bits(a), 0x07060302u);
}
__device__ __forceinline__ float fast_tanh(float x) {
  float e = exp2f(x * 2.8853900817779268f);  // 2*log2(e)
  return 1.0f - 2.0f * __builtin_amdgcn_rcpf(e + 1.0f);
}

// ---------------- prep (unchanged from R2) ----------------
__global__ void prep_kernel(const float* __restrict__ C, short* __restrict__ Bp,
                            float* __restrict__ bias) {
  int b = blockIdx.x;
  if (b < 256) {
    int i = b;
    int n = threadIdx.x;
    const float* c = C + (i * 256 + n) * 6;
    float c2 = c[2], c3 = c[3], c4_ = c[4], c5 = c[5];
    float w0 = c2 + 2.0f * c4_;
    float w1 = c3 + 3.0f * c5;
    unsigned int r0 = pack_bf16_rne(w0, w1);
    unsigned int r1 = pack_bf16_rne(c4_, c5);
    int ks = i >> 3;
    int lane = (((i >> 1) & 3) << 4) | (n & 15);
    int ntg = n >> 4;
    int off = (((ks * 16 + ntg) * 64 + lane) << 3) + ((i & 1) << 2);
    *(uint2*)(Bp + off) = make_uint2(r0, r1);
  } else {
    int w = threadIdx.x >> 6;
    int t = threadIdx.x & 63;
    int n = (b - 256) * 4 + w;
    float s = 0.0f;
#pragma unroll
    for (int r = 0; r < 4; ++r) {
      int i = t + r * 64;
      const float* c = C + (i * 256 + n) * 6;
      s += c[1] + c[3] + c[5];
    }
#pragma unroll
    for (int off = 32; off > 0; off >>= 1) s += __shfl_down(s, off);
    if (t == 0) bias[n] = s;
  }
}

// ---------------- fused tanh + powers + GEMM ----------------
__global__ __launch_bounds__(256, 2) void fibkan_gemm(
    const float* __restrict__ x, const short* __restrict__ Bp,
    const float* __restrict__ bias, float* __restrict__ y) {
  __shared__ unsigned short tl[128 * 260];  // 66560 B -> 2 blocks/CU
  const int tid = threadIdx.x;
  const int lane = tid & 63;
  const int wv = tid >> 6;  // M-strip 0..3 (rows wv*32 .. wv*32+31)
  const int mb = blockIdx.x >> 1, nb = blockIdx.x & 1;

  // ---- stage t = tanh(x) tile: 128 rows x 256 cols ----
  {
    const float4* xp = (const float4*)(x + mb * 128 * 256);
#pragma unroll 4
    for (int it = 0; it < 32; ++it) {
      int j = tid + it * 256;
      int row = j >> 6, c4i = j & 63;
      float4 v = xp[j];
      float t0 = fast_tanh(v.x), t1 = fast_tanh(v.y);
      float t2 = fast_tanh(v.z), t3 = fast_tanh(v.w);
      uint2 pk = make_uint2(pack_bf16_rne(t0, t1), pack_bf16_rne(t2, t3));
      *(uint2*)&tl[row * 260 + c4i * 4] = pk;
    }
  }
  __syncthreads();

  const int lhi = lane >> 4, llo = lane & 15;
  // t u32 for (mt, ks): tp0 + mt*16*260 + ks*8   (shorts)
  const unsigned short* tp0 = &tl[(wv * 32 + llo) * 260 + lhi * 2];
  // B-frag (ks, nt): bp[ks*1024 + nt*64]; identical across the 4 waves
  const bf16x8* bp = (const bf16x8*)Bp + (nb * 8) * 64 + lane;

  // bias preload (held across K-loop)
  float bv[8];
#pragma unroll
  for (int nt = 0; nt < 8; ++nt) bv[nt] = bias[nb * 128 + nt * 16 + llo];

  f32x4 acc[2][8] = {};
  unsigned int tA[2][2];
  bf16x8 bB[2][8];
#pragma unroll
  for (int p = 0; p < 2; ++p) {
#pragma unroll
    for (int mt = 0; mt < 2; ++mt)
      tA[p][mt] = *(const unsigned int*)(tp0 + mt * 16 * 260 + p * 8);
#pragma unroll
    for (int nt = 0; nt < 8; ++nt) bB[p][nt] = bp[p * 1024 + nt * 64];
  }

  // one K-step: consume parity buffer p at step ks, then (if pf) reload
  // the SAME buffer for ks+2 -> loads in flight ~1.5 iterations, no rotation.
  auto halfstep = [&](int ks, int p, bool pf) {
    bf16x8 af[2];
#pragma unroll
    for (int mt = 0; mt < 2; ++mt) {
      unsigned int tp2 = tA[p][mt];
      float ta = __uint_as_float(tp2 << 16);
      float tb = __uint_as_float(tp2 & 0xffff0000u);
      float ta2 = ta * ta, tb2 = tb * tb;
      float ta3 = ta2 * ta, tb3 = tb2 * tb;
      float ta4 = ta2 * ta2, tb4 = tb2 * tb2;
      uint4v u = {pack_bf16_trunc(ta, ta2), pack_bf16_trunc(ta3, ta4),
                  pack_bf16_trunc(tb, tb2), pack_bf16_trunc(tb3, tb4)};
      af[mt] = __builtin_bit_cast(bf16x8, u);
    }
#pragma unroll
    for (int nt = 0; nt < 8; ++nt) {
      acc[0][nt] = __builtin_amdgcn_mfma_f32_16x16x32_bf16(af[0], bB[p][nt],
                                                           acc[0][nt], 0, 0, 0);
      acc[1][nt] = __builtin_amdgcn_mfma_f32_16x16x32_bf16(af[1], bB[p][nt],
                                                           acc[1][nt], 0, 0, 0);
    }
    if (pf) {
#pragma unroll
      for (int nt = 0; nt < 8; ++nt) bB[p][nt] = bp[(ks + 2) * 1024 + nt * 64];
#pragma unroll
      for (int mt = 0; mt < 2; ++mt)
        tA[p][mt] =
            *(const unsigned int*)(tp0 + mt * 16 * 260 + (ks + 2) * 8);
    }
  };

  for (int ks2 = 0; ks2 < 15; ++ks2) {
    halfstep(2 * ks2, 0, true);
    halfstep(2 * ks2 + 1, 1, true);
  }
  halfstep(30, 0, false);
  halfstep(31, 1, false);

  // epilogue: D col = nt*16 + llo (+nb*128), row = wv*32 + mt*16 + lhi*4 + r
  const int col0 = nb * 128 + llo;
  const int row0 = mb * 128 + wv * 32 + lhi * 4;
#pragma unroll
  for (int nt = 0; nt < 8; ++nt) {
#pragma unroll
    for (int mt = 0; mt < 2; ++mt) {
#pragma unroll
      for (int r = 0; r < 4; ++r) {
        y[(row0 + mt * 16 + r) * 256 + col0 + nt * 16] = acc[mt][nt][r] + bv[nt];
      }
    }
  }
}

extern "C" void kernel_launch(void* const* d_in, const int* in_sizes, int n_in,
                              void* d_out, int out_size, void* d_ws, size_t ws_size,
                              hipStream_t stream) {
  const float* x = (const float*)d_in[0];        // [32768, 256] f32
  const float* C = (const float*)d_in[1];        // [256, 256, 6] f32
  float* y = (float*)d_out;                      // [32768, 256] f32
  float* bias = (float*)d_ws;                    // 256 f32
  short* Bp = (short*)((char*)d_ws + 1024);      // 1024x256 bf16, frag-ordered
  prep_kernel<<<320, 256, 0, stream>>>(C, Bp, bias);
  fibkan_gemm<<<512, 256, 0, stream>>>(x, Bp, bias, y);
}

// Round 4
// 104.424 us; speedup vs baseline: 1.0447x; 1.0447x over previous
//
#include <hip/hip_runtime.h>
#include <stdint.h>

// FibonacciKAN: y[b,o] = sum_i sum_d F_d(tanh(x[b,i])) * C[i,o,d]
// F0..F5 = {0, 1, t, t^2+1, t^3+2t, t^4+3t^2+1}
// => y = bias[o] + sum_i ( t*W0 + t^2*W1 + t^3*W2 + t^4*W3 )[i,o]
// GEMM: M=32768, N=256, K=1024, bf16 MFMA 16x16x32.
//
// R4: full-N blocks (tile 128x256, grid 256, 512 thr) -> x read ONCE from HBM
// (32 MB not 64). Staging split into two 128-col chunks; chunk-1 global loads
// overlap the first half of the K-loop (regs), converted to LDS mid-loop.
// Attacks the phase-lockstep serialization (grid == resident count, no
// natural stagger). MFMA order + roundings identical -> absmax unchanged.

typedef short bf16x8 __attribute__((ext_vector_type(8)));
typedef float f32x4 __attribute__((ext_vector_type(4)));
typedef unsigned int uint4v __attribute__((ext_vector_type(4)));

__device__ __forceinline__ unsigned int pack_bf16_trunc(float a, float b) {
  return __builtin_amdgcn_perm(__float_as_uint(b), __float_as_uint(a), 0x07060302u);
}
__device__ __forceinline__ unsigned int round_bf16_bits(float a) {
  unsigned int u = __float_as_uint(a);
  return u + 0x7fffu + ((u >> 16) & 1u);
}
__device__ __forceinline__ unsigned int pack_bf16_rne(float a, float b) {
  return __builtin_amdgcn_perm(round_bf16_bits(b), round_bf16_bits(a), 0x07060302u);
}
__device__ __forceinline__ float fast_tanh(float x) {
  float e = exp2f(x * 2.8853900817779268f);  // 2*log2(e)
  return 1.0f - 2.0f * __builtin_amdgcn_rcpf(e + 1.0f);
}

// ---------------- prep (unchanged from R2/R3) ----------------
__global__ void prep_kernel(const float* __restrict__ C, short* __restrict__ Bp,
                            float* __restrict__ bias) {
  int b = blockIdx.x;
  if (b < 256) {
    int i = b;
    int n = threadIdx.x;
    const float* c = C + (i * 256 + n) * 6;
    float c2 = c[2], c3 = c[3], c4_ = c[4], c5 = c[5];
    float w0 = c2 + 2.0f * c4_;
    float w1 = c3 + 3.0f * c5;
    unsigned int r0 = pack_bf16_rne(w0, w1);
    unsigned int r1 = pack_bf16_rne(c4_, c5);
    int ks = i >> 3;
    int lane = (((i >> 1) & 3) << 4) | (n & 15);
    int ntg = n >> 4;
    int off = (((ks * 16 + ntg) * 64 + lane) << 3) + ((i & 1) << 2);
    *(uint2*)(Bp + off) = make_uint2(r0, r1);
  } else {
    int w = threadIdx.x >> 6;
    int t = threadIdx.x & 63;
    int n = (b - 256) * 4 + w;
    float s = 0.0f;
#pragma unroll
    for (int r = 0; r < 4; ++r) {
      int i = t + r * 64;
      const float* c = C + (i * 256 + n) * 6;
      s += c[1] + c[3] + c[5];
    }
#pragma unroll
    for (int off = 32; off > 0; off >>= 1) s += __shfl_down(s, off);
    if (t == 0) bias[n] = s;
  }
}

// ---------------- fused tanh + powers + GEMM ----------------
// Block: 128 rows x full 256 cols, 512 threads = 8 waves (4 M-strips x 2
// N-halves). Grid 256 = 1 block/CU, 2 waves/SIMD.
__global__ __launch_bounds__(512, 2) void fibkan_gemm(
    const float* __restrict__ x, const short* __restrict__ Bp,
    const float* __restrict__ bias, float* __restrict__ y) {
  __shared__ unsigned short tl[128 * 260];  // 66560 B
  const int tid = threadIdx.x;
  const int lane = tid & 63;
  const int wv = tid >> 6;
  const int wm = wv >> 1, wn = wv & 1;
  const int mb = blockIdx.x;
  const int lhi = lane >> 4, llo = lane & 15;

  const float4* xp = (const float4*)(x) + mb * 128 * 64;  // x row = 64 float4

  // bias preload (global, drains at first barrier — tiny)
  float bv[8];
#pragma unroll
  for (int nt = 0; nt < 8; ++nt) bv[nt] = bias[wn * 128 + nt * 16 + llo];

  // ---- chunk 0: cols 0..127 -> tanh -> LDS ----
  {
#pragma unroll
    for (int it = 0; it < 8; ++it) {
      int j = tid + it * 512;           // 0..4095
      int row = j >> 5, c = j & 31;     // c = float4 col 0..31
      float4 v = xp[row * 64 + c];
      uint2 pk = make_uint2(pack_bf16_rne(fast_tanh(v.x), fast_tanh(v.y)),
                            pack_bf16_rne(fast_tanh(v.z), fast_tanh(v.w)));
      *(uint2*)&tl[row * 260 + c * 4] = pk;
    }
  }
  __syncthreads();

  // t u32 for (mt, ks): tp0 + mt*16*260 + ks*8 (shorts)
  const unsigned short* tp0 = &tl[(wm * 32 + llo) * 260 + lhi * 2];
  // B-frag (ks, nt): bp[ks*1024 + nt*64]; shared by the 4 waves of each half
  const bf16x8* bp = (const bf16x8*)Bp + (wn * 8) * 64 + lane;

  f32x4 acc[2][8] = {};
  unsigned int tA[2][2];
  bf16x8 bB[2][8];
#pragma unroll
  for (int p = 0; p < 2; ++p) {
#pragma unroll
    for (int mt = 0; mt < 2; ++mt)
      tA[p][mt] = *(const unsigned int*)(tp0 + mt * 16 * 260 + p * 8);
#pragma unroll
    for (int nt = 0; nt < 8; ++nt) bB[p][nt] = bp[p * 1024 + nt * 64];
  }

  // ---- chunk 1 global loads: in flight across the first half-K-loop ----
  float4 xb[8];
#pragma unroll
  for (int it = 0; it < 8; ++it) {
    int j = tid + it * 512;
    int row = j >> 5, c = j & 31;
    xb[it] = xp[row * 64 + 32 + c];
  }

  auto halfstep = [&](int ks, int p, bool pfA, bool pfB) {
    bf16x8 af[2];
#pragma unroll
    for (int mt = 0; mt < 2; ++mt) {
      unsigned int tp2 = tA[p][mt];
      float ta = __uint_as_float(tp2 << 16);
      float tb = __uint_as_float(tp2 & 0xffff0000u);
      float ta2 = ta * ta, tb2 = tb * tb;
      float ta3 = ta2 * ta, tb3 = tb2 * tb;
      float ta4 = ta2 * ta2, tb4 = tb2 * tb2;
      uint4v u = {pack_bf16_trunc(ta, ta2), pack_bf16_trunc(ta3, ta4),
                  pack_bf16_trunc(tb, tb2), pack_bf16_trunc(tb3, tb4)};
      af[mt] = __builtin_bit_cast(bf16x8, u);
    }
#pragma unroll
    for (int nt = 0; nt < 8; ++nt) {
      acc[0][nt] = __builtin_amdgcn_mfma_f32_16x16x32_bf16(af[0], bB[p][nt],
                                                           acc[0][nt], 0, 0, 0);
      acc[1][nt] = __builtin_amdgcn_mfma_f32_16x16x32_bf16(af[1], bB[p][nt],
                                                           acc[1][nt], 0, 0, 0);
    }
    if (pfB) {
#pragma unroll
      for (int nt = 0; nt < 8; ++nt) bB[p][nt] = bp[(ks + 2) * 1024 + nt * 64];
    }
    if (pfA) {
#pragma unroll
      for (int mt = 0; mt < 2; ++mt)
        tA[p][mt] = *(const unsigned int*)(tp0 + mt * 16 * 260 + (ks + 2) * 8);
    }
  };

  // first half: ks 0..15 over chunk-0 t-data
  for (int ks2 = 0; ks2 < 7; ++ks2) {
    halfstep(2 * ks2, 0, true, true);
    halfstep(2 * ks2 + 1, 1, true, true);
  }
  halfstep(14, 0, false, true);  // tA ks16 not in LDS yet
  halfstep(15, 1, false, true);

  // ---- chunk 1: tanh -> LDS (region disjoint from chunk 0 -> no barrier
  // needed before the writes; one barrier after) ----
#pragma unroll
  for (int it = 0; it < 8; ++it) {
    int j = tid + it * 512;
    int row = j >> 5, c = j & 31;
    float4 v = xb[it];
    uint2 pk = make_uint2(pack_bf16_rne(fast_tanh(v.x), fast_tanh(v.y)),
                          pack_bf16_rne(fast_tanh(v.z), fast_tanh(v.w)));
    *(uint2*)&tl[row * 260 + 128 + c * 4] = pk;
  }
  __syncthreads();
#pragma unroll
  for (int p = 0; p < 2; ++p)
#pragma unroll
    for (int mt = 0; mt < 2; ++mt)
      tA[p][mt] = *(const unsigned int*)(tp0 + mt * 16 * 260 + (16 + p) * 8);

  // second half: ks 16..31
  for (int ks2 = 8; ks2 < 15; ++ks2) {
    halfstep(2 * ks2, 0, true, true);
    halfstep(2 * ks2 + 1, 1, true, true);
  }
  halfstep(30, 0, false, false);
  halfstep(31, 1, false, false);

  // epilogue: D col = wn*128 + nt*16 + llo, row = wm*32 + mt*16 + lhi*4 + r
  const int col0 = wn * 128 + llo;
  const int row0 = mb * 128 + wm * 32 + lhi * 4;
#pragma unroll
  for (int nt = 0; nt < 8; ++nt) {
#pragma unroll
    for (int mt = 0; mt < 2; ++mt) {
#pragma unroll
      for (int r = 0; r < 4; ++r) {
        y[(row0 + mt * 16 + r) * 256 + col0 + nt * 16] = acc[mt][nt][r] + bv[nt];
      }
    }
  }
}

extern "C" void kernel_launch(void* const* d_in, const int* in_sizes, int n_in,
                              void* d_out, int out_size, void* d_ws, size_t ws_size,
                              hipStream_t stream) {
  const float* x = (const float*)d_in[0];        // [32768, 256] f32
  const float* C = (const float*)d_in[1];        // [256, 256, 6] f32
  float* y = (float*)d_out;                      // [32768, 256] f32
  float* bias = (float*)d_ws;                    // 256 f32
  short* Bp = (short*)((char*)d_ws + 1024);      // 1024x256 bf16, frag-ordered
  prep_kernel<<<320, 256, 0, stream>>>(C, Bp, bias);
  fibkan_gemm<<<256, 512, 0, stream>>>(x, Bp, bias, y);
}

// Round 5
// 103.944 us; speedup vs baseline: 1.0495x; 1.0046x over previous
//
#include <hip/hip_runtime.h>
#include <stdint.h>

// FibonacciKAN: y[b,o] = sum_i sum_d F_d(tanh(x[b,i])) * C[i,o,d]
// F0..F5 = {0, 1, t, t^2+1, t^3+2t, t^4+3t^2+1}
// => y = bias[o] + sum_i ( t*W0 + t^2*W1 + t^3*W2 + t^4*W3 )[i,o]
// GEMM: M=32768, N=256, K=1024, bf16 MFMA 16x16x32.
//
// R5: wave tile 64x128 (mt=4, nt=8), 4 waves/block (2M x 2N), 256 thr,
// grid 256 -> 1 wave/SIMD. Halves per-CU B-frag L1 port pressure
// (64KB -> 32KB per K-step vs ~37KB available in the 620 MFMA cycles):
// R4 was L1-bound at ~103 B/cyc demanded vs ~60 B/cyc/CU sustainable.
// VGPR budget 512 at 1 wave/SIMD -> acc128 + dbuf B + x-prefetch all fit.
// MFMA (m,n,k) order + roundings identical -> absmax unchanged.

typedef short bf16x8 __attribute__((ext_vector_type(8)));
typedef float f32x4 __attribute__((ext_vector_type(4)));
typedef unsigned int uint4v __attribute__((ext_vector_type(4)));

__device__ __forceinline__ unsigned int pack_bf16_trunc(float a, float b) {
  return __builtin_amdgcn_perm(__float_as_uint(b), __float_as_uint(a), 0x07060302u);
}
__device__ __forceinline__ unsigned int round_bf16_bits(float a) {
  unsigned int u = __float_as_uint(a);
  return u + 0x7fffu + ((u >> 16) & 1u);
}
__device__ __forceinline__ unsigned int pack_bf16_rne(float a, float b) {
  return __builtin_amdgcn_perm(round_bf16_bits(b), round_bf16_bits(a), 0x07060302u);
}
__device__ __forceinline__ float fast_tanh(float x) {
  float e = exp2f(x * 2.8853900817779268f);  // 2*log2(e)
  return 1.0f - 2.0f * __builtin_amdgcn_rcpf(e + 1.0f);
}

// ---------------- prep (unchanged) ----------------
__global__ void prep_kernel(const float* __restrict__ C, short* __restrict__ Bp,
                            float* __restrict__ bias) {
  int b = blockIdx.x;
  if (b < 256) {
    int i = b;
    int n = threadIdx.x;
    const float* c = C + (i * 256 + n) * 6;
    float c2 = c[2], c3 = c[3], c4_ = c[4], c5 = c[5];
    float w0 = c2 + 2.0f * c4_;
    float w1 = c3 + 3.0f * c5;
    unsigned int r0 = pack_bf16_rne(w0, w1);
    unsigned int r1 = pack_bf16_rne(c4_, c5);
    int ks = i >> 3;
    int lane = (((i >> 1) & 3) << 4) | (n & 15);
    int ntg = n >> 4;
    int off = (((ks * 16 + ntg) * 64 + lane) << 3) + ((i & 1) << 2);
    *(uint2*)(Bp + off) = make_uint2(r0, r1);
  } else {
    int w = threadIdx.x >> 6;
    int t = threadIdx.x & 63;
    int n = (b - 256) * 4 + w;
    float s = 0.0f;
#pragma unroll
    for (int r = 0; r < 4; ++r) {
      int i = t + r * 64;
      const float* c = C + (i * 256 + n) * 6;
      s += c[1] + c[3] + c[5];
    }
#pragma unroll
    for (int off = 32; off > 0; off >>= 1) s += __shfl_down(s, off);
    if (t == 0) bias[n] = s;
  }
}

// ---------------- fused tanh + powers + GEMM ----------------
// Block: 128 rows x 256 cols, 256 threads = 4 waves (2 M x 2 N).
// Wave tile: 64 rows (mt=4) x 128 cols (nt=8). Grid 256 = 1 block/CU.
__global__ __launch_bounds__(256, 1) void fibkan_gemm(
    const float* __restrict__ x, const short* __restrict__ Bp,
    const float* __restrict__ bias, float* __restrict__ y) {
  __shared__ unsigned short tl[128 * 260];  // 66560 B
  const int tid = threadIdx.x;
  const int lane = tid & 63;
  const int wv = tid >> 6;
  const int wm = wv >> 1, wn = wv & 1;
  const int mb = blockIdx.x;
  const int lhi = lane >> 4, llo = lane & 15;

  const float4* xp = (const float4*)(x) + mb * 128 * 64;  // x row = 64 float4

  float bv[8];
#pragma unroll
  for (int nt = 0; nt < 8; ++nt) bv[nt] = bias[wn * 128 + nt * 16 + llo];

  // ---- chunk 0: cols 0..127 -> tanh -> LDS ----
#pragma unroll
  for (int it = 0; it < 16; ++it) {
    int j = tid + it * 256;           // 0..4095
    int row = j >> 5, c = j & 31;     // c = float4 col 0..31
    float4 v = xp[row * 64 + c];
    uint2 pk = make_uint2(pack_bf16_rne(fast_tanh(v.x), fast_tanh(v.y)),
                          pack_bf16_rne(fast_tanh(v.z), fast_tanh(v.w)));
    *(uint2*)&tl[row * 260 + c * 4] = pk;
  }
  __syncthreads();

  // t u32 for (mt, ks): tp0 + mt*16*260 + ks*8 (shorts)
  const unsigned short* tp0 = &tl[(wm * 64 + llo) * 260 + lhi * 2];
  // B-frag (ks, nt): bp[ks*1024 + nt*64]
  const bf16x8* bp = (const bf16x8*)Bp + (wn * 8) * 64 + lane;

  f32x4 acc[4][8] = {};
  unsigned int tA[2][4];
  bf16x8 bB[2][8];
#pragma unroll
  for (int p = 0; p < 2; ++p) {
#pragma unroll
    for (int mt = 0; mt < 4; ++mt)
      tA[p][mt] = *(const unsigned int*)(tp0 + mt * 16 * 260 + p * 8);
#pragma unroll
    for (int nt = 0; nt < 8; ++nt) bB[p][nt] = bp[p * 1024 + nt * 64];
  }

  // ---- chunk 1 global loads: in flight across the first half-K-loop ----
  float4 xb[16];
#pragma unroll
  for (int it = 0; it < 16; ++it) {
    int j = tid + it * 256;
    int row = j >> 5, c = j & 31;
    xb[it] = xp[row * 64 + 32 + c];
  }

  auto halfstep = [&](int ks, int p, bool pfA, bool pfB) {
    bf16x8 af[4];
#pragma unroll
    for (int mt = 0; mt < 4; ++mt) {
      unsigned int tp2 = tA[p][mt];
      float ta = __uint_as_float(tp2 << 16);
      float tb = __uint_as_float(tp2 & 0xffff0000u);
      float ta2 = ta * ta, tb2 = tb * tb;
      float ta3 = ta2 * ta, tb3 = tb2 * tb;
      float ta4 = ta2 * ta2, tb4 = tb2 * tb2;
      uint4v u = {pack_bf16_trunc(ta, ta2), pack_bf16_trunc(ta3, ta4),
                  pack_bf16_trunc(tb, tb2), pack_bf16_trunc(tb3, tb4)};
      af[mt] = __builtin_bit_cast(bf16x8, u);
    }
#pragma unroll
    for (int nt = 0; nt < 8; ++nt) {
#pragma unroll
      for (int mt = 0; mt < 4; ++mt) {
        acc[mt][nt] = __builtin_amdgcn_mfma_f32_16x16x32_bf16(
            af[mt], bB[p][nt], acc[mt][nt], 0, 0, 0);
      }
    }
    if (pfB) {
#pragma unroll
      for (int nt = 0; nt < 8; ++nt) bB[p][nt] = bp[(ks + 2) * 1024 + nt * 64];
    }
    if (pfA) {
#pragma unroll
      for (int mt = 0; mt < 4; ++mt)
        tA[p][mt] = *(const unsigned int*)(tp0 + mt * 16 * 260 + (ks + 2) * 8);
    }
  };

  // first half: ks 0..15 over chunk-0 t-data
  for (int ks2 = 0; ks2 < 7; ++ks2) {
    halfstep(2 * ks2, 0, true, true);
    halfstep(2 * ks2 + 1, 1, true, true);
  }
  halfstep(14, 0, false, true);  // tA ks16 not in LDS yet
  halfstep(15, 1, false, true);

  // ---- chunk 1: tanh -> LDS (disjoint region; one barrier after) ----
#pragma unroll
  for (int it = 0; it < 16; ++it) {
    int j = tid + it * 256;
    int row = j >> 5, c = j & 31;
    float4 v = xb[it];
    uint2 pk = make_uint2(pack_bf16_rne(fast_tanh(v.x), fast_tanh(v.y)),
                          pack_bf16_rne(fast_tanh(v.z), fast_tanh(v.w)));
    *(uint2*)&tl[row * 260 + 128 + c * 4] = pk;
  }
  __syncthreads();
#pragma unroll
  for (int p = 0; p < 2; ++p)
#pragma unroll
    for (int mt = 0; mt < 4; ++mt)
      tA[p][mt] = *(const unsigned int*)(tp0 + mt * 16 * 260 + (16 + p) * 8);

  // second half: ks 16..31
  for (int ks2 = 8; ks2 < 15; ++ks2) {
    halfstep(2 * ks2, 0, true, true);
    halfstep(2 * ks2 + 1, 1, true, true);
  }
  halfstep(30, 0, false, false);
  halfstep(31, 1, false, false);

  // epilogue: D col = wn*128 + nt*16 + llo, row = wm*64 + mt*16 + lhi*4 + r
  const int col0 = wn * 128 + llo;
  const int row0 = mb * 128 + wm * 64 + lhi * 4;
#pragma unroll
  for (int nt = 0; nt < 8; ++nt) {
#pragma unroll
    for (int mt = 0; mt < 4; ++mt) {
#pragma unroll
      for (int r = 0; r < 4; ++r) {
        y[(row0 + mt * 16 + r) * 256 + col0 + nt * 16] = acc[mt][nt][r] + bv[nt];
      }
    }
  }
}

extern "C" void kernel_launch(void* const* d_in, const int* in_sizes, int n_in,
                              void* d_out, int out_size, void* d_ws, size_t ws_size,
                              hipStream_t stream) {
  const float* x = (const float*)d_in[0];        // [32768, 256] f32
  const float* C = (const float*)d_in[1];        // [256, 256, 6] f32
  float* y = (float*)d_out;                      // [32768, 256] f32
  float* bias = (float*)d_ws;                    // 256 f32
  short* Bp = (short*)((char*)d_ws + 1024);      // 1024x256 bf16, frag-ordered
  prep_kernel<<<320, 256, 0, stream>>>(C, Bp, bias);
  fibkan_gemm<<<256, 256, 0, stream>>>(x, Bp, bias, y);
}

// Round 6
// 101.612 us; speedup vs baseline: 1.0736x; 1.0230x over previous
//
#include <hip/hip_runtime.h>
#include <stdint.h>

// FibonacciKAN: y[b,o] = sum_i sum_d F_d(tanh(x[b,i])) * C[i,o,d]
// F0..F5 = {0, 1, t, t^2+1, t^3+2t, t^4+3t^2+1}
// => y = bias[o] + sum_i ( t*W0 + t^2*W1 + t^3*W2 + t^4*W3 )[i,o]
// GEMM: M=32768, N=256, K=1024, bf16 MFMA 16x16x32.
//
// R6: wave tile 64x64 (mt=4, nt=4). Satisfies BOTH constraints discovered in
// R4/R5: (1) B-frag L1 pressure = 211/mt B/cyc/CU -> mt=4 gives 53 < ~60
// sustainable (R4's mt=2 was 106, L1-bound); (2) total waves = 2048 -> 2
// waves/SIMD resident for latency hiding (R5's 1 w/SIMD was latency-bound,
// gemm 75us profiled). Block = 64 rows x 256 cols (4 waves, one n-quarter
// each), grid 512, 2 blocks/CU, x read once. acc=64 VGPRs.
// MFMA (m,n,k) order + roundings identical -> absmax unchanged (9.766e-4).

typedef short bf16x8 __attribute__((ext_vector_type(8)));
typedef float f32x4 __attribute__((ext_vector_type(4)));
typedef unsigned int uint4v __attribute__((ext_vector_type(4)));

__device__ __forceinline__ unsigned int pack_bf16_trunc(float a, float b) {
  return __builtin_amdgcn_perm(__float_as_uint(b), __float_as_uint(a), 0x07060302u);
}
__device__ __forceinline__ unsigned int round_bf16_bits(float a) {
  unsigned int u = __float_as_uint(a);
  return u + 0x7fffu + ((u >> 16) & 1u);
}
__device__ __forceinline__ unsigned int pack_bf16_rne(float a, float b) {
  return __builtin_amdgcn_perm(round_bf16_bits(b), round_bf16_bits(a), 0x07060302u);
}
__device__ __forceinline__ float fast_tanh(float x) {
  float e = exp2f(x * 2.8853900817779268f);  // 2*log2(e)
  return 1.0f - 2.0f * __builtin_amdgcn_rcpf(e + 1.0f);
}

// ---------------- prep (unchanged) ----------------
__global__ void prep_kernel(const float* __restrict__ C, short* __restrict__ Bp,
                            float* __restrict__ bias) {
  int b = blockIdx.x;
  if (b < 256) {
    int i = b;
    int n = threadIdx.x;
    const float* c = C + (i * 256 + n) * 6;
    float c2 = c[2], c3 = c[3], c4_ = c[4], c5 = c[5];
    float w0 = c2 + 2.0f * c4_;
    float w1 = c3 + 3.0f * c5;
    unsigned int r0 = pack_bf16_rne(w0, w1);
    unsigned int r1 = pack_bf16_rne(c4_, c5);
    int ks = i >> 3;
    int lane = (((i >> 1) & 3) << 4) | (n & 15);
    int ntg = n >> 4;
    int off = (((ks * 16 + ntg) * 64 + lane) << 3) + ((i & 1) << 2);
    *(uint2*)(Bp + off) = make_uint2(r0, r1);
  } else {
    int w = threadIdx.x >> 6;
    int t = threadIdx.x & 63;
    int n = (b - 256) * 4 + w;
    float s = 0.0f;
#pragma unroll
    for (int r = 0; r < 4; ++r) {
      int i = t + r * 64;
      const float* c = C + (i * 256 + n) * 6;
      s += c[1] + c[3] + c[5];
    }
#pragma unroll
    for (int off = 32; off > 0; off >>= 1) s += __shfl_down(s, off);
    if (t == 0) bias[n] = s;
  }
}

// ---------------- fused tanh + powers + GEMM ----------------
// Block: 64 rows x 256 cols, 256 threads = 4 waves, wave wv owns n-quarter
// wv*64..wv*64+63. Wave tile 64x64 = mt4 x nt4 of 16x16x32 MFMA.
// Grid 512 = 2 blocks/CU, 2 waves/SIMD.
__global__ __launch_bounds__(256, 2) void fibkan_gemm(
    const float* __restrict__ x, const short* __restrict__ Bp,
    const float* __restrict__ bias, float* __restrict__ y) {
  __shared__ unsigned short tl[64 * 260];  // 33280 B -> 2 blocks/CU
  const int tid = threadIdx.x;
  const int lane = tid & 63;
  const int wv = tid >> 6;  // n-quarter
  const int mb = blockIdx.x;
  const int lhi = lane >> 4, llo = lane & 15;

  const float4* xp = (const float4*)(x) + mb * 64 * 64;  // x row = 64 float4

  float bv[4];
#pragma unroll
  for (int nt = 0; nt < 4; ++nt) bv[nt] = bias[wv * 64 + nt * 16 + llo];

  // ---- stage t = tanh(x): 64 rows x 256 cols, single shot ----
#pragma unroll
  for (int it = 0; it < 16; ++it) {
    int j = tid + it * 256;           // 0..4095 float4 index
    int row = j >> 6, c = j & 63;     // 64 float4 per row
    float4 v = xp[row * 64 + c];
    uint2 pk = make_uint2(pack_bf16_rne(fast_tanh(v.x), fast_tanh(v.y)),
                          pack_bf16_rne(fast_tanh(v.z), fast_tanh(v.w)));
    *(uint2*)&tl[row * 260 + c * 4] = pk;
  }
  __syncthreads();

  // t u32 for (mt, ks): tp0 + mt*16*260 + ks*8 (shorts)
  const unsigned short* tp0 = &tl[llo * 260 + lhi * 2];
  // B-frag (ks, nt): bp[ks*1024 + nt*64]
  const bf16x8* bp = (const bf16x8*)Bp + (wv * 4) * 64 + lane;

  f32x4 acc[4][4] = {};
  unsigned int tA[2][4];
  bf16x8 bB[2][4];
#pragma unroll
  for (int p = 0; p < 2; ++p) {
#pragma unroll
    for (int mt = 0; mt < 4; ++mt)
      tA[p][mt] = *(const unsigned int*)(tp0 + mt * 16 * 260 + p * 8);
#pragma unroll
    for (int nt = 0; nt < 4; ++nt) bB[p][nt] = bp[p * 1024 + nt * 64];
  }

  auto halfstep = [&](int ks, int p, bool pf) {
    bf16x8 af[4];
#pragma unroll
    for (int mt = 0; mt < 4; ++mt) {
      unsigned int tp2 = tA[p][mt];
      float ta = __uint_as_float(tp2 << 16);
      float tb = __uint_as_float(tp2 & 0xffff0000u);
      float ta2 = ta * ta, tb2 = tb * tb;
      float ta3 = ta2 * ta, tb3 = tb2 * tb;
      float ta4 = ta2 * ta2, tb4 = tb2 * tb2;
      uint4v u = {pack_bf16_trunc(ta, ta2), pack_bf16_trunc(ta3, ta4),
                  pack_bf16_trunc(tb, tb2), pack_bf16_trunc(tb3, tb4)};
      af[mt] = __builtin_bit_cast(bf16x8, u);
    }
#pragma unroll
    for (int nt = 0; nt < 4; ++nt) {
#pragma unroll
      for (int mt = 0; mt < 4; ++mt) {
        acc[mt][nt] = __builtin_amdgcn_mfma_f32_16x16x32_bf16(
            af[mt], bB[p][nt], acc[mt][nt], 0, 0, 0);
      }
    }
    if (pf) {
#pragma unroll
      for (int nt = 0; nt < 4; ++nt) bB[p][nt] = bp[(ks + 2) * 1024 + nt * 64];
#pragma unroll
      for (int mt = 0; mt < 4; ++mt)
        tA[p][mt] = *(const unsigned int*)(tp0 + mt * 16 * 260 + (ks + 2) * 8);
    }
  };

  // ks 0..29 with prefetch (k+2 <= 31), tail 30,31 without
  for (int ks2 = 0; ks2 < 15; ++ks2) {
    halfstep(2 * ks2, 0, true);
    halfstep(2 * ks2 + 1, 1, true);
  }
  halfstep(30, 0, false);
  halfstep(31, 1, false);

  // epilogue: D col = wv*64 + nt*16 + llo, row = mt*16 + lhi*4 + r
  const int col0 = wv * 64 + llo;
  const int row0 = mb * 64 + lhi * 4;
#pragma unroll
  for (int nt = 0; nt < 4; ++nt) {
#pragma unroll
    for (int mt = 0; mt < 4; ++mt) {
#pragma unroll
      for (int r = 0; r < 4; ++r) {
        y[(row0 + mt * 16 + r) * 256 + col0 + nt * 16] = acc[mt][nt][r] + bv[nt];
      }
    }
  }
}

extern "C" void kernel_launch(void* const* d_in, const int* in_sizes, int n_in,
                              void* d_out, int out_size, void* d_ws, size_t ws_size,
                              hipStream_t stream) {
  const float* x = (const float*)d_in[0];        // [32768, 256] f32
  const float* C = (const float*)d_in[1];        // [256, 256, 6] f32
  float* y = (float*)d_out;                      // [32768, 256] f32
  float* bias = (float*)d_ws;                    // 256 f32
  short* Bp = (short*)((char*)d_ws + 1024);      // 1024x256 bf16, frag-ordered
  prep_kernel<<<320, 256, 0, stream>>>(C, Bp, bias);
  fibkan_gemm<<<512, 256, 0, stream>>>(x, Bp, bias, y);
}